// Round 1
// baseline (821.640 us; speedup 1.0000x reference)
//
#include <hip/hip_runtime.h>
#include <hip/hip_bf16.h>

#define NN 20000      // nodes
#define NE 320000     // edges
#define HD 256        // hidden dim
#define NB 2          // batch
#define FIN 128

// ---------------- init: zero counters + pool ----------------
__global__ __launch_bounds__(256) void init_kernel(int* cnt, double* pool) {
    int i = blockIdx.x * 256 + threadIdx.x;
    if (i < NN) cnt[i] = 0;
    if (i < NB * HD) pool[i] = 0.0;
}

// ---------------- count incoming edges per dst ----------------
__global__ __launch_bounds__(256) void count_kernel(const int* __restrict__ dst, int* cnt) {
    int e = blockIdx.x * 256 + threadIdx.x;
    if (e < NE) atomicAdd(&cnt[dst[e]], 1);
}

// ---------------- single-block exclusive scan + dinv ----------------
__global__ __launch_bounds__(1024) void scan_kernel(int* cnt, int* rstart, float* dinv) {
    __shared__ int sums[1024];
    const int CH = 20;                       // 1024*20 = 20480 >= 20000
    int t = threadIdx.x;
    int start = t * CH;
    int end = min(start + CH, NN);
    int local = 0;
    for (int n = start; n < end; ++n) {
        int c = cnt[n];
        local += c;
        dinv[n] = rsqrtf(1.0f + (float)c);   // deg includes self-loop
    }
    sums[t] = local;
    __syncthreads();
    for (int off = 1; off < 1024; off <<= 1) {
        int v = (t >= off) ? sums[t - off] : 0;
        __syncthreads();
        sums[t] += v;
        __syncthreads();
    }
    int run = (t == 0) ? 0 : sums[t - 1];
    for (int n = start; n < end; ++n) {
        int c = cnt[n];
        rstart[n] = run;
        cnt[n] = run;                        // becomes the bucket cursor
        run += c;
    }
    if (end == NN) rstart[NN] = run;
}

// ---------------- bucket edges by dst, precompute weights ----------------
__global__ __launch_bounds__(256) void bucket_kernel(const int* __restrict__ src,
                                                     const int* __restrict__ dst,
                                                     int* cursor, int* esrc, float* ewt,
                                                     const float* __restrict__ dinv) {
    int e = blockIdx.x * 256 + threadIdx.x;
    if (e >= NE) return;
    int s = src[e], d = dst[e];
    int pos = atomicAdd(&cursor[d], 1);
    esrc[pos] = s;
    ewt[pos] = dinv[s] * dinv[d];
}

// ---------------- fp32 tiled GEMM: C[M,256] = A[M,K] @ W[K,256] ----------------
template <int K>
__global__ __launch_bounds__(256) void gemm_kernel(const float* __restrict__ A,
                                                   const float* __restrict__ W,
                                                   float* __restrict__ C) {
    const int BM = 64, BN = 64, BK = 16;
    __shared__ float As[BK][BM + 1];
    __shared__ float Bs[BK][BN];
    int bm = blockIdx.x * BM;
    int bn = blockIdx.y * BN;
    int t = threadIdx.x;
    int tx = t & 15, ty = t >> 4;
    int arow = t >> 2, acol = (t & 3) * 4;
    int brow = t >> 4, bcol = (t & 15) * 4;
    float acc[4][4] = {};
    for (int k0 = 0; k0 < K; k0 += BK) {
        float4 a4 = *(const float4*)&A[(size_t)(bm + arow) * K + k0 + acol];
        float4 b4 = *(const float4*)&W[(size_t)(k0 + brow) * HD + bn + bcol];
        __syncthreads();
        As[acol + 0][arow] = a4.x;
        As[acol + 1][arow] = a4.y;
        As[acol + 2][arow] = a4.z;
        As[acol + 3][arow] = a4.w;
        *(float4*)&Bs[brow][bcol] = b4;
        __syncthreads();
#pragma unroll
        for (int kk = 0; kk < BK; ++kk) {
            float a[4], bv[4];
#pragma unroll
            for (int i = 0; i < 4; ++i) a[i] = As[kk][ty * 4 + i];
#pragma unroll
            for (int j = 0; j < 4; ++j) bv[j] = Bs[kk][tx * 4 + j];
#pragma unroll
            for (int i = 0; i < 4; ++i)
#pragma unroll
                for (int j = 0; j < 4; ++j) acc[i][j] += a[i] * bv[j];
        }
    }
#pragma unroll
    for (int i = 0; i < 4; ++i) {
        float4 v = make_float4(acc[i][0], acc[i][1], acc[i][2], acc[i][3]);
        *(float4*)&C[(size_t)(bm + ty * 4 + i) * HD + bn + tx * 4] = v;
    }
}

// ---------------- aggregation: out = relu(bias + self + sum_in w*h[src]) ----------------
__global__ __launch_bounds__(256) void agg_kernel(const float* __restrict__ h,
                                                  const float* __restrict__ bias,
                                                  const int* __restrict__ rstart,
                                                  const int* __restrict__ esrc,
                                                  const float* __restrict__ ewt,
                                                  const float* __restrict__ dinv,
                                                  float* __restrict__ out) {
    int n = blockIdx.x;
    int b = blockIdx.y;
    int f = threadIdx.x;
    float dn = dinv[n];
    float acc = h[((size_t)b * NN + n) * HD + f] * dn * dn;  // self loop
    int e0 = rstart[n], e1 = rstart[n + 1];
    for (int e = e0; e < e1; ++e) {
        int s = esrc[e];
        float w = ewt[e];
        acc += h[((size_t)b * NN + s) * HD + f] * w;
    }
    out[((size_t)b * NN + n) * HD + f] = fmaxf(acc + bias[f], 0.0f);
}

// ---------------- column sums for mean pool ----------------
__global__ __launch_bounds__(256) void colsum_kernel(const float* __restrict__ h, double* pool) {
    const int R = 256;
    int b = blockIdx.y;
    int r0 = blockIdx.x * R;
    int r1 = min(r0 + R, NN);
    int f = threadIdx.x;
    float s = 0.0f;
    for (int r = r0; r < r1; ++r) s += h[((size_t)b * NN + r) * HD + f];
    atomicAdd(&pool[b * HD + f], (double)s);
}

// ---------------- head: out[b] = mean_h . Wl + bl ----------------
__global__ __launch_bounds__(256) void head_kernel(const double* __restrict__ pool,
                                                   const float* __restrict__ Wl,
                                                   const float* __restrict__ bl,
                                                   float* __restrict__ out) {
    __shared__ double red[256];
    int f = threadIdx.x;
    for (int b = 0; b < NB; ++b) {
        double v = pool[b * HD + f] * (1.0 / NN) * (double)Wl[f];
        red[f] = v;
        __syncthreads();
        for (int off = 128; off; off >>= 1) {
            if (f < off) red[f] += red[f + off];
            __syncthreads();
        }
        if (f == 0) out[b] = (float)(red[0] + (double)bl[0]);
        __syncthreads();
    }
}

extern "C" void kernel_launch(void* const* d_in, const int* in_sizes, int n_in,
                              void* d_out, int out_size, void* d_ws, size_t ws_size,
                              hipStream_t stream) {
    const float* x  = (const float*)d_in[0];
    const int* eidx = (const int*)d_in[1];
    const float* W1 = (const float*)d_in[2];
    const float* b1 = (const float*)d_in[3];
    const float* W2 = (const float*)d_in[4];
    const float* b2 = (const float*)d_in[5];
    const float* W3 = (const float*)d_in[6];
    const float* b3 = (const float*)d_in[7];
    const float* Wl = (const float*)d_in[8];
    const float* bl = (const float*)d_in[9];
    float* out = (float*)d_out;

    const int* src = eidx;
    const int* dst = eidx + NE;

    // workspace layout
    size_t BNH = (size_t)NB * NN * HD;   // 10,240,000 floats
    float* bufA  = (float*)d_ws;
    float* bufB  = bufA + BNH;
    float* dinv  = bufB + BNH;
    float* ewt   = dinv + NN;
    int*   cnt   = (int*)(ewt + NE);
    int*   rstart= cnt + NN;
    int*   esrc  = rstart + (NN + 1);
    double* pool = (double*)(esrc + NE + 1);   // +1 pad for 8B alignment

    const int M = NB * NN;                     // 40000 rows

    init_kernel<<<(NN + 255) / 256, 256, 0, stream>>>(cnt, pool);
    count_kernel<<<(NE + 255) / 256, 256, 0, stream>>>(dst, cnt);
    scan_kernel<<<1, 1024, 0, stream>>>(cnt, rstart, dinv);
    bucket_kernel<<<(NE + 255) / 256, 256, 0, stream>>>(src, dst, cnt, esrc, ewt, dinv);

    dim3 ggrid(M / 64, HD / 64);
    dim3 agrid(NN, NB);

    // layer 1
    gemm_kernel<FIN><<<ggrid, 256, 0, stream>>>(x, W1, bufA);
    agg_kernel<<<agrid, 256, 0, stream>>>(bufA, b1, rstart, esrc, ewt, dinv, bufB);
    // layer 2
    gemm_kernel<HD><<<ggrid, 256, 0, stream>>>(bufB, W2, bufA);
    agg_kernel<<<agrid, 256, 0, stream>>>(bufA, b2, rstart, esrc, ewt, dinv, bufB);
    // layer 3
    gemm_kernel<HD><<<ggrid, 256, 0, stream>>>(bufB, W3, bufA);
    agg_kernel<<<agrid, 256, 0, stream>>>(bufA, b3, rstart, esrc, ewt, dinv, bufB);

    // mean pool + head
    colsum_kernel<<<dim3((NN + 255) / 256, NB), 256, 0, stream>>>(bufB, pool);
    head_kernel<<<1, 256, 0, stream>>>(pool, Wl, bl, out);
}

// Round 2
// 476.580 us; speedup vs baseline: 1.7240x; 1.7240x over previous
//
#include <hip/hip_runtime.h>
#include <hip/hip_bf16.h>

#define NN 20000      // nodes
#define NE 320000     // edges
#define HD 256        // hidden dim
#define NB 2          // batch
#define FIN 128
#define MP 40064      // NB*NN padded to multiple of 128 (313*128)

typedef __attribute__((ext_vector_type(8))) short bf16x8;
typedef __attribute__((ext_vector_type(4))) float f32x4;

__device__ inline float bf2f(ushort u) {
    union { unsigned int i; float f; } c; c.i = ((unsigned int)u) << 16; return c.f;
}
__device__ inline ushort f2bf(float f) {
    __hip_bfloat16 h = __float2bfloat16(f);
    return *reinterpret_cast<ushort*>(&h);
}

// ---------------- init: zero counters + pool ----------------
__global__ __launch_bounds__(256) void init_kernel(int* cnt, double* pool) {
    int i = blockIdx.x * 256 + threadIdx.x;
    if (i < NN) cnt[i] = 0;
    if (i < NB * HD) pool[i] = 0.0;
}

// ---------------- count incoming edges per dst ----------------
__global__ __launch_bounds__(256) void count_kernel(const int* __restrict__ dst, int* cnt) {
    int e = blockIdx.x * 256 + threadIdx.x;
    if (e < NE) atomicAdd(&cnt[dst[e]], 1);
}

// ---------------- single-block exclusive scan + dinv ----------------
__global__ __launch_bounds__(1024) void scan_kernel(int* cnt, int* rstart, float* dinv) {
    __shared__ int sums[1024];
    const int CH = 20;
    int t = threadIdx.x;
    int start = t * CH;
    int end = min(start + CH, NN);
    int local = 0;
    for (int n = start; n < end; ++n) {
        int c = cnt[n];
        local += c;
        dinv[n] = rsqrtf(1.0f + (float)c);   // deg includes self-loop
    }
    sums[t] = local;
    __syncthreads();
    for (int off = 1; off < 1024; off <<= 1) {
        int v = (t >= off) ? sums[t - off] : 0;
        __syncthreads();
        sums[t] += v;
        __syncthreads();
    }
    int run = (t == 0) ? 0 : sums[t - 1];
    for (int n = start; n < end; ++n) {
        int c = cnt[n];
        rstart[n] = run;
        cnt[n] = run;                        // becomes the bucket cursor
        run += c;
    }
    if (end == NN) rstart[NN] = run;
}

// ---------------- bucket edges by dst, precompute weights ----------------
__global__ __launch_bounds__(256) void bucket_kernel(const int* __restrict__ src,
                                                     const int* __restrict__ dst,
                                                     int* cursor, int2* edge2,
                                                     const float* __restrict__ dinv) {
    int e = blockIdx.x * 256 + threadIdx.x;
    if (e >= NE) return;
    int s = src[e], d = dst[e];
    int pos = atomicAdd(&cursor[d], 1);
    float w = dinv[s] * dinv[d];
    edge2[pos] = make_int2(s, __float_as_int(w));
}

// ---------------- cast x fp32 -> bf16 ----------------
__global__ __launch_bounds__(256) void castx_kernel(const float* __restrict__ x,
                                                    ushort* __restrict__ xb) {
    int i = blockIdx.x * 256 + threadIdx.x;   // processes 4 floats
    float4 v = *(const float4*)&x[(size_t)i * 4];
    ushort4 o;
    o.x = f2bf(v.x); o.y = f2bf(v.y); o.z = f2bf(v.z); o.w = f2bf(v.w);
    *(ushort4*)&xb[(size_t)i * 4] = o;
}

// ---------------- W [K][256] fp32 -> WT [256][K] bf16 ----------------
__global__ __launch_bounds__(256) void wcast_kernel(const float* __restrict__ W,
                                                    ushort* __restrict__ WT, int K) {
    int i = blockIdx.x * 256 + threadIdx.x;   // i over input elems, coalesced read
    if (i >= K * HD) return;
    int k = i >> 8, n = i & 255;
    WT[n * K + k] = f2bf(W[i]);
}

// ---------------- aggregation: out[b,n,:] = dinv[n]^2*h[b,n,:] + sum_e w*h[b,src,:]
template <int FEAT>
__global__ __launch_bounds__(256) void agg_kernel(const ushort* __restrict__ h,
                                                  const int2* __restrict__ edge2,
                                                  const int* __restrict__ rstart,
                                                  const float* __restrict__ dinv,
                                                  ushort* __restrict__ out) {
    constexpr int EL = FEAT / 64;             // elems per lane (2 or 4)
    int wid = __builtin_amdgcn_readfirstlane((int)(threadIdx.x >> 6));
    int l = threadIdx.x & 63;
    int n = blockIdx.x * 4 + wid;
    int b = blockIdx.y;
    int bb = b * NN;
    float dn = dinv[n];
    float acc[EL];
    // self-loop term
    {
        const ushort* hr = h + (size_t)(bb + n) * FEAT + l * EL;
        float w = dn * dn;
        if constexpr (EL == 4) {
            uint2 v = *(const uint2*)hr;
            acc[0] = w * bf2f((ushort)(v.x & 0xffff));
            acc[1] = w * bf2f((ushort)(v.x >> 16));
            acc[2] = w * bf2f((ushort)(v.y & 0xffff));
            acc[3] = w * bf2f((ushort)(v.y >> 16));
        } else {
            unsigned int v = *(const unsigned int*)hr;
            acc[0] = w * bf2f((ushort)(v & 0xffff));
            acc[1] = w * bf2f((ushort)(v >> 16));
        }
    }
    int e0 = rstart[n], e1 = rstart[n + 1];
    int2 ed;
    if (e0 < e1) ed = edge2[e0];
    for (int e = e0; e < e1; ++e) {
        int s = ed.x;
        float w = __int_as_float(ed.y);
        if (e + 1 < e1) ed = edge2[e + 1];
        const ushort* hr = h + (size_t)(bb + s) * FEAT + l * EL;
        if constexpr (EL == 4) {
            uint2 v = *(const uint2*)hr;
            acc[0] += w * bf2f((ushort)(v.x & 0xffff));
            acc[1] += w * bf2f((ushort)(v.x >> 16));
            acc[2] += w * bf2f((ushort)(v.y & 0xffff));
            acc[3] += w * bf2f((ushort)(v.y >> 16));
        } else {
            unsigned int v = *(const unsigned int*)hr;
            acc[0] += w * bf2f((ushort)(v & 0xffff));
            acc[1] += w * bf2f((ushort)(v >> 16));
        }
    }
    ushort* op = out + (size_t)(bb + n) * FEAT + l * EL;
    if constexpr (EL == 4) {
        uint2 o;
        o.x = (unsigned int)f2bf(acc[0]) | ((unsigned int)f2bf(acc[1]) << 16);
        o.y = (unsigned int)f2bf(acc[2]) | ((unsigned int)f2bf(acc[3]) << 16);
        *(uint2*)op = o;
    } else {
        unsigned int o = (unsigned int)f2bf(acc[0]) | ((unsigned int)f2bf(acc[1]) << 16);
        *(unsigned int*)op = o;
    }
}

// ---------------- MFMA GEMM: C[MP,256] = relu(A[MP,K] @ BT[256,K]^T + bias), bf16
template <int K>
__global__ __launch_bounds__(256) void gemm_kernel(const ushort* __restrict__ A,
                                                   const ushort* __restrict__ BT,
                                                   const float* __restrict__ bias,
                                                   ushort* __restrict__ C) {
    const int BK = 64;
    __shared__ ushort As[128 * BK];   // 16KB, XOR-swizzled rows of 8 16B-chunks
    __shared__ ushort Bs[128 * BK];
    int t = threadIdx.x;
    int l = t & 63, w = t >> 6;
    int wr = w >> 1, wc = w & 1;
    size_t bm = (size_t)blockIdx.x * 128;
    int bn = blockIdx.y * 128;
    f32x4 acc[4][4] = {};
    for (int kt = 0; kt < K; kt += BK) {
        uint4 ra[4], rb[4];
#pragma unroll
        for (int i = 0; i < 4; ++i) {
            int c = i * 256 + t;           // chunk 0..1023
            int row = c >> 3, kc = c & 7;  // 8 chunks (16B) per row
            ra[i] = *(const uint4*)&A[(bm + row) * K + kt + kc * 8];
            rb[i] = *(const uint4*)&BT[(size_t)(bn + row) * K + kt + kc * 8];
        }
        __syncthreads();
#pragma unroll
        for (int i = 0; i < 4; ++i) {
            int c = i * 256 + t;
            int row = c >> 3, kc = c & 7;
            int sw = kc ^ (row & 7);
            *(uint4*)&As[row * 64 + sw * 8] = ra[i];
            *(uint4*)&Bs[row * 64 + sw * 8] = rb[i];
        }
        __syncthreads();
#pragma unroll
        for (int s = 0; s < 2; ++s) {
            bf16x8 af[4], bfr[4];
#pragma unroll
            for (int m = 0; m < 4; ++m) {
                int row = wr * 64 + m * 16 + (l & 15);
                int chunk = s * 4 + (l >> 4);
                af[m] = *(const bf16x8*)&As[row * 64 + (chunk ^ (row & 7)) * 8];
            }
#pragma unroll
            for (int n = 0; n < 4; ++n) {
                int row = wc * 64 + n * 16 + (l & 15);
                int chunk = s * 4 + (l >> 4);
                bfr[n] = *(const bf16x8*)&Bs[row * 64 + (chunk ^ (row & 7)) * 8];
            }
#pragma unroll
            for (int m = 0; m < 4; ++m)
#pragma unroll
                for (int n = 0; n < 4; ++n)
                    acc[m][n] = __builtin_amdgcn_mfma_f32_16x16x32_bf16(af[m], bfr[n], acc[m][n], 0, 0, 0);
        }
    }
    // epilogue: bias + relu + bf16 store. D layout: col=l&15, row=(l>>4)*4+j
#pragma unroll
    for (int m = 0; m < 4; ++m) {
#pragma unroll
        for (int n = 0; n < 4; ++n) {
            int col = bn + wc * 64 + n * 16 + (l & 15);
            float bv = bias[col];
#pragma unroll
            for (int j = 0; j < 4; ++j) {
                size_t row = bm + wr * 64 + m * 16 + (l >> 4) * 4 + j;
                float v = fmaxf(acc[m][n][j] + bv, 0.0f);
                C[row * HD + col] = f2bf(v);
            }
        }
    }
}

// ---------------- column sums for mean pool (bf16 input) ----------------
__global__ __launch_bounds__(256) void colsum_kernel(const ushort* __restrict__ h, double* pool) {
    const int R = 256;
    int b = blockIdx.y;
    int r0 = blockIdx.x * R;
    int r1 = min(r0 + R, NN);
    int f = threadIdx.x;
    float s = 0.0f;
    for (int r = r0; r < r1; ++r) s += bf2f(h[((size_t)b * NN + r) * HD + f]);
    atomicAdd(&pool[b * HD + f], (double)s);
}

// ---------------- head: out[b] = mean_h . Wl + bl ----------------
__global__ __launch_bounds__(256) void head_kernel(const double* __restrict__ pool,
                                                   const float* __restrict__ Wl,
                                                   const float* __restrict__ bl,
                                                   float* __restrict__ out) {
    __shared__ double red[256];
    int f = threadIdx.x;
    for (int b = 0; b < NB; ++b) {
        double v = pool[b * HD + f] * (1.0 / NN) * (double)Wl[f];
        red[f] = v;
        __syncthreads();
        for (int off = 128; off; off >>= 1) {
            if (f < off) red[f] += red[f + off];
            __syncthreads();
        }
        if (f == 0) out[b] = (float)(red[0] + (double)bl[0]);
        __syncthreads();
    }
}

extern "C" void kernel_launch(void* const* d_in, const int* in_sizes, int n_in,
                              void* d_out, int out_size, void* d_ws, size_t ws_size,
                              hipStream_t stream) {
    const float* x  = (const float*)d_in[0];
    const int* eidx = (const int*)d_in[1];
    const float* W1 = (const float*)d_in[2];
    const float* b1 = (const float*)d_in[3];
    const float* W2 = (const float*)d_in[4];
    const float* b2 = (const float*)d_in[5];
    const float* W3 = (const float*)d_in[6];
    const float* b3 = (const float*)d_in[7];
    const float* Wl = (const float*)d_in[8];
    const float* bl = (const float*)d_in[9];
    float* out = (float*)d_out;

    const int* src = eidx;
    const int* dst = eidx + NE;

    // ---- workspace layout (bytes, 256B-aligned blocks) ----
    char* p = (char*)d_ws;
    auto alloc = [&](size_t bytes) { char* r = p; p += (bytes + 255) & ~(size_t)255; return r; };
    ushort* xb    = (ushort*)alloc((size_t)MP * FIN * 2);
    ushort* aggx  = (ushort*)alloc((size_t)MP * FIN * 2);
    ushort* bufA  = (ushort*)alloc((size_t)MP * HD * 2);
    ushort* bufB  = (ushort*)alloc((size_t)MP * HD * 2);
    ushort* w1t   = (ushort*)alloc((size_t)HD * FIN * 2);
    ushort* w2t   = (ushort*)alloc((size_t)HD * HD * 2);
    ushort* w3t   = (ushort*)alloc((size_t)HD * HD * 2);
    float*  dinv  = (float*)alloc(NN * 4);
    int2*   edge2 = (int2*)alloc((size_t)NE * 8);
    int*    cnt   = (int*)alloc(NN * 4);
    int*    rstart= (int*)alloc((NN + 1) * 4);
    double* pool  = (double*)alloc(NB * HD * 8);

    // ---- graph build (per call; ws is re-poisoned every launch) ----
    init_kernel<<<(NN + 255) / 256, 256, 0, stream>>>(cnt, pool);
    count_kernel<<<(NE + 255) / 256, 256, 0, stream>>>(dst, cnt);
    scan_kernel<<<1, 1024, 0, stream>>>(cnt, rstart, dinv);
    bucket_kernel<<<(NE + 255) / 256, 256, 0, stream>>>(src, dst, cnt, edge2, dinv);

    // ---- casts ----
    castx_kernel<<<(NB * NN * FIN / 4 + 255) / 256, 256, 0, stream>>>(x, xb);
    wcast_kernel<<<(FIN * HD + 255) / 256, 256, 0, stream>>>(W1, w1t, FIN);
    wcast_kernel<<<(HD * HD + 255) / 256, 256, 0, stream>>>(W2, w2t, HD);
    wcast_kernel<<<(HD * HD + 255) / 256, 256, 0, stream>>>(W3, w3t, HD);

    dim3 agrid(NN / 4, NB);
    dim3 ggrid(MP / 128, HD / 128);

    // layer 1: h1 = relu(agg(x) @ W1 + b1)
    agg_kernel<FIN><<<agrid, 256, 0, stream>>>(xb, edge2, rstart, dinv, aggx);
    gemm_kernel<FIN><<<ggrid, 256, 0, stream>>>(aggx, w1t, b1, bufA);
    // layer 2: h2 = relu(agg(h1) @ W2 + b2)
    agg_kernel<HD><<<agrid, 256, 0, stream>>>(bufA, edge2, rstart, dinv, bufB);
    gemm_kernel<HD><<<ggrid, 256, 0, stream>>>(bufB, w2t, b2, bufA);
    // layer 3: h3 = relu(agg(h2) @ W3 + b3)
    agg_kernel<HD><<<agrid, 256, 0, stream>>>(bufA, edge2, rstart, dinv, bufB);
    gemm_kernel<HD><<<ggrid, 256, 0, stream>>>(bufB, w3t, b3, bufA);

    // mean pool + head
    colsum_kernel<<<dim3((NN + 255) / 256, NB), 256, 0, stream>>>(bufA, pool);
    head_kernel<<<1, 256, 0, stream>>>(pool, Wl, bl, out);
}

// Round 3
// 453.275 us; speedup vs baseline: 1.8127x; 1.0514x over previous
//
#include <hip/hip_runtime.h>
#include <hip/hip_bf16.h>
#include <type_traits>

#define NN 20000      // nodes
#define NE 320000     // edges
#define HD 256        // hidden dim
#define NB 2          // batch
#define FIN 128
#define MP 40064      // NB*NN padded to multiple of 128 (313*128)

typedef __attribute__((ext_vector_type(8))) short bf16x8;
typedef __attribute__((ext_vector_type(4))) float f32x4;

__device__ inline float bf2f(ushort u) {
    union { unsigned int i; float f; } c; c.i = ((unsigned int)u) << 16; return c.f;
}
__device__ inline ushort f2bf(float f) {
    __hip_bfloat16 h = __float2bfloat16(f);
    return *reinterpret_cast<ushort*>(&h);
}

// ---------------- init: zero counters + pool ----------------
__global__ __launch_bounds__(256) void init_kernel(int* cnt, double* pool) {
    int i = blockIdx.x * 256 + threadIdx.x;
    if (i < NN) cnt[i] = 0;
    if (i < NB * HD) pool[i] = 0.0;
}

// ---------------- count incoming edges per dst ----------------
__global__ __launch_bounds__(256) void count_kernel(const int* __restrict__ dst, int* cnt) {
    int e = blockIdx.x * 256 + threadIdx.x;
    if (e < NE) atomicAdd(&cnt[dst[e]], 1);
}

// ---------------- single-block exclusive scan + dinv ----------------
__global__ __launch_bounds__(1024) void scan_kernel(int* cnt, int* rstart, float* dinv) {
    __shared__ int sums[1024];
    const int CH = 20;
    int t = threadIdx.x;
    int start = t * CH;
    int end = min(start + CH, NN);
    int local = 0;
    for (int n = start; n < end; ++n) {
        int c = cnt[n];
        local += c;
        dinv[n] = rsqrtf(1.0f + (float)c);   // deg includes self-loop
    }
    sums[t] = local;
    __syncthreads();
    for (int off = 1; off < 1024; off <<= 1) {
        int v = (t >= off) ? sums[t - off] : 0;
        __syncthreads();
        sums[t] += v;
        __syncthreads();
    }
    int run = (t == 0) ? 0 : sums[t - 1];
    for (int n = start; n < end; ++n) {
        int c = cnt[n];
        rstart[n] = run;
        cnt[n] = run;                        // becomes the bucket cursor
        run += c;
    }
    if (end == NN) rstart[NN] = run;
}

// ---------------- bucket edges by dst, precompute weights ----------------
__global__ __launch_bounds__(256) void bucket_kernel(const int* __restrict__ src,
                                                     const int* __restrict__ dst,
                                                     int* cursor, int2* edge2,
                                                     const float* __restrict__ dinv) {
    int e = blockIdx.x * 256 + threadIdx.x;
    if (e >= NE) return;
    int s = src[e], d = dst[e];
    int pos = atomicAdd(&cursor[d], 1);
    float w = dinv[s] * dinv[d];
    edge2[pos] = make_int2(s, __float_as_int(w));
}

// ---------------- cast x fp32 [B][N][FIN] -> bf16 interleaved [(n*2+b)][FIN] ----------------
__global__ __launch_bounds__(256) void castx_kernel(const float* __restrict__ x,
                                                    ushort* __restrict__ xb) {
    int i = blockIdx.x * 256 + threadIdx.x;   // processes 4 floats
    size_t g = (size_t)i * 4;
    int b = (int)(g / ((size_t)NN * FIN));
    size_t rem = g - (size_t)b * NN * FIN;
    int n = (int)(rem / FIN);
    int f = (int)(rem % FIN);
    float4 v = *(const float4*)&x[g];
    ushort4 o;
    o.x = f2bf(v.x); o.y = f2bf(v.y); o.z = f2bf(v.z); o.w = f2bf(v.w);
    *(ushort4*)&xb[((size_t)n * NB + b) * FIN + f] = o;
}

// ---------------- W [K][256] fp32 -> WT [256][K] bf16 ----------------
__global__ __launch_bounds__(256) void wcast_kernel(const float* __restrict__ W,
                                                    ushort* __restrict__ WT, int K) {
    int i = blockIdx.x * 256 + threadIdx.x;   // i over input elems, coalesced read
    if (i >= K * HD) return;
    int k = i >> 8, n = i & 255;
    WT[n * K + k] = f2bf(W[i]);
}

// ---------------- aggregation over interleaved rows: one wave per node ----------------
// row(n) = [b0 feats | b1 feats], RW = NB*FEAT elems. out[n] = dinv^2*h[n] + sum w*h[src]
template <int FEAT>
__global__ __launch_bounds__(256) void agg_kernel(const ushort* __restrict__ h,
                                                  const int2* __restrict__ edge2,
                                                  const int* __restrict__ rstart,
                                                  const float* __restrict__ dinv,
                                                  ushort* __restrict__ out) {
    constexpr int RW = NB * FEAT;             // 256 or 512 elems per row
    constexpr int EL = RW / 64;               // 4 or 8 elems per lane
    constexpr int NU = EL / 2;                // uints per lane
    using VecT = std::conditional_t<EL == 8, uint4, uint2>;
    union UV { VecT v; unsigned int u[NU]; };

    int wid = threadIdx.x >> 6;
    int l = threadIdx.x & 63;
    int n = blockIdx.x * 4 + wid;
    const ushort* hb = h + l * EL;            // lane-offset base
    float dn = dinv[n];
    float acc[EL];
    {   // self-loop term
        UV s; s.v = *(const VecT*)&hb[(size_t)n * RW];
        float w = dn * dn;
#pragma unroll
        for (int k = 0; k < NU; ++k) {
            acc[2 * k]     = w * bf2f((ushort)(s.u[k] & 0xffff));
            acc[2 * k + 1] = w * bf2f((ushort)(s.u[k] >> 16));
        }
    }
    int e0 = rstart[n], e1 = rstart[n + 1];
    int2 edA, edB;
    UV vA;
    if (e0 < e1) edA = edge2[e0];
    if (e0 + 1 < e1) edB = edge2[e0 + 1];
    if (e0 < e1) vA.v = *(const VecT*)&hb[(size_t)edA.x * RW];
    for (int e = e0; e < e1; ++e) {
        float w = __int_as_float(edA.y);
        UV v = vA;
        edA = edB;
        if (e + 2 < e1) edB = edge2[e + 2];
        if (e + 1 < e1) vA.v = *(const VecT*)&hb[(size_t)edA.x * RW];
#pragma unroll
        for (int k = 0; k < NU; ++k) {
            acc[2 * k]     += w * bf2f((ushort)(v.u[k] & 0xffff));
            acc[2 * k + 1] += w * bf2f((ushort)(v.u[k] >> 16));
        }
    }
    UV o;
#pragma unroll
    for (int k = 0; k < NU; ++k)
        o.u[k] = (unsigned int)f2bf(acc[2 * k]) | ((unsigned int)f2bf(acc[2 * k + 1]) << 16);
    *(VecT*)&((ushort*)out)[(size_t)n * RW + l * EL] = o.v;
}

// ---------------- MFMA GEMM: C[MP,256] = relu(A[MP,K] @ BT[256,K]^T + bias), bf16
template <int K>
__global__ __launch_bounds__(256) void gemm_kernel(const ushort* __restrict__ A,
                                                   const ushort* __restrict__ BT,
                                                   const float* __restrict__ bias,
                                                   ushort* __restrict__ C) {
    const int BK = 64;
    __shared__ ushort As[128 * BK];   // 16KB, XOR-swizzled rows of 8 16B-chunks
    __shared__ ushort Bs[128 * BK];
    int t = threadIdx.x;
    int l = t & 63, w = t >> 6;
    int wr = w >> 1, wc = w & 1;
    size_t bm = (size_t)blockIdx.x * 128;
    int bn = blockIdx.y * 128;
    f32x4 acc[4][4] = {};
    for (int kt = 0; kt < K; kt += BK) {
        uint4 ra[4], rb[4];
#pragma unroll
        for (int i = 0; i < 4; ++i) {
            int c = i * 256 + t;           // chunk 0..1023
            int row = c >> 3, kc = c & 7;  // 8 chunks (16B) per row
            ra[i] = *(const uint4*)&A[(bm + row) * K + kt + kc * 8];
            rb[i] = *(const uint4*)&BT[(size_t)(bn + row) * K + kt + kc * 8];
        }
        __syncthreads();
#pragma unroll
        for (int i = 0; i < 4; ++i) {
            int c = i * 256 + t;
            int row = c >> 3, kc = c & 7;
            int sw = kc ^ (row & 7);
            *(uint4*)&As[row * 64 + sw * 8] = ra[i];
            *(uint4*)&Bs[row * 64 + sw * 8] = rb[i];
        }
        __syncthreads();
#pragma unroll
        for (int s = 0; s < 2; ++s) {
            bf16x8 af[4], bfr[4];
#pragma unroll
            for (int m = 0; m < 4; ++m) {
                int row = wr * 64 + m * 16 + (l & 15);
                int chunk = s * 4 + (l >> 4);
                af[m] = *(const bf16x8*)&As[row * 64 + (chunk ^ (row & 7)) * 8];
            }
#pragma unroll
            for (int n = 0; n < 4; ++n) {
                int row = wc * 64 + n * 16 + (l & 15);
                int chunk = s * 4 + (l >> 4);
                bfr[n] = *(const bf16x8*)&Bs[row * 64 + (chunk ^ (row & 7)) * 8];
            }
#pragma unroll
            for (int m = 0; m < 4; ++m)
#pragma unroll
                for (int n = 0; n < 4; ++n)
                    acc[m][n] = __builtin_amdgcn_mfma_f32_16x16x32_bf16(af[m], bfr[n], acc[m][n], 0, 0, 0);
        }
    }
    // epilogue: bias + relu + bf16 store. D layout: col=l&15, row=(l>>4)*4+j
#pragma unroll
    for (int m = 0; m < 4; ++m) {
#pragma unroll
        for (int n = 0; n < 4; ++n) {
            int col = bn + wc * 64 + n * 16 + (l & 15);
            float bv = bias[col];
#pragma unroll
            for (int j = 0; j < 4; ++j) {
                size_t row = bm + wr * 64 + m * 16 + (l >> 4) * 4 + j;
                float v = fmaxf(acc[m][n][j] + bv, 0.0f);
                C[row * HD + col] = f2bf(v);
            }
        }
    }
}

// ---------------- column sums for mean pool (bf16, interleaved rows) ----------------
// node-group (rows 2n,2n+1) = 1KB = 256 uints; thread t reads uint t of the group.
__global__ __launch_bounds__(256) void colsum_kernel(const ushort* __restrict__ h, double* pool) {
    const int NCH = 32;                       // nodes per block; 625 blocks
    int n0 = blockIdx.x * NCH;
    int t = threadIdx.x;
    const unsigned int* hu = (const unsigned int*)h;
    int b = t >> 7;                            // elem g=2t: row parity
    int f0 = (2 * t) & 255;
    float s0 = 0.0f, s1 = 0.0f;
    for (int n = n0; n < n0 + NCH; ++n) {
        unsigned int u = hu[(size_t)n * (NB * HD / 2) + t];
        s0 += bf2f((ushort)(u & 0xffff));
        s1 += bf2f((ushort)(u >> 16));
    }
    atomicAdd(&pool[b * HD + f0], (double)s0);
    atomicAdd(&pool[b * HD + f0 + 1], (double)s1);
}

// ---------------- head: out[b] = mean_h . Wl + bl ----------------
__global__ __launch_bounds__(256) void head_kernel(const double* __restrict__ pool,
                                                   const float* __restrict__ Wl,
                                                   const float* __restrict__ bl,
                                                   float* __restrict__ out) {
    __shared__ double red[256];
    int f = threadIdx.x;
    for (int b = 0; b < NB; ++b) {
        double v = pool[b * HD + f] * (1.0 / NN) * (double)Wl[f];
        red[f] = v;
        __syncthreads();
        for (int off = 128; off; off >>= 1) {
            if (f < off) red[f] += red[f + off];
            __syncthreads();
        }
        if (f == 0) out[b] = (float)(red[0] + (double)bl[0]);
        __syncthreads();
    }
}

extern "C" void kernel_launch(void* const* d_in, const int* in_sizes, int n_in,
                              void* d_out, int out_size, void* d_ws, size_t ws_size,
                              hipStream_t stream) {
    const float* x  = (const float*)d_in[0];
    const int* eidx = (const int*)d_in[1];
    const float* W1 = (const float*)d_in[2];
    const float* b1 = (const float*)d_in[3];
    const float* W2 = (const float*)d_in[4];
    const float* b2 = (const float*)d_in[5];
    const float* W3 = (const float*)d_in[6];
    const float* b3 = (const float*)d_in[7];
    const float* Wl = (const float*)d_in[8];
    const float* bl = (const float*)d_in[9];
    float* out = (float*)d_out;

    const int* src = eidx;
    const int* dst = eidx + NE;

    // ---- workspace layout (bytes, 256B-aligned blocks) ----
    char* p = (char*)d_ws;
    auto alloc = [&](size_t bytes) { char* r = p; p += (bytes + 255) & ~(size_t)255; return r; };
    ushort* xb    = (ushort*)alloc((size_t)MP * FIN * 2);
    ushort* aggx  = (ushort*)alloc((size_t)MP * FIN * 2);
    ushort* bufA  = (ushort*)alloc((size_t)MP * HD * 2);
    ushort* bufB  = (ushort*)alloc((size_t)MP * HD * 2);
    ushort* w1t   = (ushort*)alloc((size_t)HD * FIN * 2);
    ushort* w2t   = (ushort*)alloc((size_t)HD * HD * 2);
    ushort* w3t   = (ushort*)alloc((size_t)HD * HD * 2);
    float*  dinv  = (float*)alloc(NN * 4);
    int2*   edge2 = (int2*)alloc((size_t)NE * 8);
    int*    cnt   = (int*)alloc(NN * 4);
    int*    rstart= (int*)alloc((NN + 1) * 4);
    double* pool  = (double*)alloc(NB * HD * 8);

    // ---- graph build (per call; ws is re-poisoned every launch) ----
    init_kernel<<<(NN + 255) / 256, 256, 0, stream>>>(cnt, pool);
    count_kernel<<<(NE + 255) / 256, 256, 0, stream>>>(dst, cnt);
    scan_kernel<<<1, 1024, 0, stream>>>(cnt, rstart, dinv);
    bucket_kernel<<<(NE + 255) / 256, 256, 0, stream>>>(src, dst, cnt, edge2, dinv);

    // ---- casts ----
    castx_kernel<<<(NB * NN * FIN / 4 + 255) / 256, 256, 0, stream>>>(x, xb);
    wcast_kernel<<<(FIN * HD + 255) / 256, 256, 0, stream>>>(W1, w1t, FIN);
    wcast_kernel<<<(HD * HD + 255) / 256, 256, 0, stream>>>(W2, w2t, HD);
    wcast_kernel<<<(HD * HD + 255) / 256, 256, 0, stream>>>(W3, w3t, HD);

    dim3 agrid(NN / 4, 1);
    dim3 ggrid(MP / 128, HD / 128);

    // layer 1: h1 = relu(agg(x) @ W1 + b1)
    agg_kernel<FIN><<<agrid, 256, 0, stream>>>(xb, edge2, rstart, dinv, aggx);
    gemm_kernel<FIN><<<ggrid, 256, 0, stream>>>(aggx, w1t, b1, bufA);
    // layer 2: h2 = relu(agg(h1) @ W2 + b2)
    agg_kernel<HD><<<agrid, 256, 0, stream>>>(bufA, edge2, rstart, dinv, bufB);
    gemm_kernel<HD><<<ggrid, 256, 0, stream>>>(bufB, w2t, b2, bufA);
    // layer 3: h3 = relu(agg(h2) @ W3 + b3)
    agg_kernel<HD><<<agrid, 256, 0, stream>>>(bufA, edge2, rstart, dinv, bufB);
    gemm_kernel<HD><<<ggrid, 256, 0, stream>>>(bufB, w3t, b3, bufA);

    // mean pool + head
    colsum_kernel<<<NN / 32, 256, 0, stream>>>(bufA, pool);
    head_kernel<<<1, 256, 0, stream>>>(pool, Wl, bl, out);
}

// Round 4
// 427.117 us; speedup vs baseline: 1.9237x; 1.0612x over previous
//
#include <hip/hip_runtime.h>
#include <hip/hip_bf16.h>
#include <type_traits>

#define NN 20000      // nodes
#define NE 320000     // edges
#define HD 256        // hidden dim
#define NB 2          // batch
#define FIN 128
#define MP 40064      // NB*NN padded to multiple of 128 (313*128)

typedef __attribute__((ext_vector_type(8))) short bf16x8;
typedef __attribute__((ext_vector_type(4))) float f32x4;

__device__ inline float bf2f(ushort u) {
    union { unsigned int i; float f; } c; c.i = ((unsigned int)u) << 16; return c.f;
}
__device__ inline ushort f2bf(float f) {
    __hip_bfloat16 h = __float2bfloat16(f);
    return *reinterpret_cast<ushort*>(&h);
}

// ---------------- count incoming edges per dst ----------------
__global__ __launch_bounds__(256) void count_kernel(const int* __restrict__ dst, int* cnt) {
    int e = blockIdx.x * 256 + threadIdx.x;
    if (e < NE) atomicAdd(&cnt[dst[e]], 1);
}

// ---------------- single-block exclusive scan + dinv ----------------
__global__ __launch_bounds__(1024) void scan_kernel(int* cnt, int* rstart, float* dinv) {
    __shared__ int sums[1024];
    const int CH = 20;
    int t = threadIdx.x;
    int start = t * CH;
    int end = min(start + CH, NN);
    int local = 0;
    for (int n = start; n < end; ++n) {
        int c = cnt[n];
        local += c;
        dinv[n] = rsqrtf(1.0f + (float)c);   // deg includes self-loop
    }
    sums[t] = local;
    __syncthreads();
    for (int off = 1; off < 1024; off <<= 1) {
        int v = (t >= off) ? sums[t - off] : 0;
        __syncthreads();
        sums[t] += v;
        __syncthreads();
    }
    int run = (t == 0) ? 0 : sums[t - 1];
    for (int n = start; n < end; ++n) {
        int c = cnt[n];
        rstart[n] = run;
        cnt[n] = run;                        // becomes the bucket cursor
        run += c;
    }
    if (end == NN) rstart[NN] = run;
}

// ---------------- bucket edges by dst, precompute weights ----------------
__global__ __launch_bounds__(256) void bucket_kernel(const int* __restrict__ src,
                                                     const int* __restrict__ dst,
                                                     int* cursor, int2* edge2,
                                                     const float* __restrict__ dinv) {
    int e = blockIdx.x * 256 + threadIdx.x;
    if (e >= NE) return;
    int s = src[e], d = dst[e];
    int pos = atomicAdd(&cursor[d], 1);
    float w = dinv[s] * dinv[d];
    edge2[pos] = make_int2(s, __float_as_int(w));
}

// ---------------- cast x fp32 [B][N][FIN] -> bf16 interleaved; also zero cnt/pool ----------------
__global__ __launch_bounds__(256) void castx_kernel(const float* __restrict__ x,
                                                    ushort* __restrict__ xb,
                                                    int* cnt, double* pool) {
    int i = blockIdx.x * 256 + threadIdx.x;   // processes 4 floats
    if (i < NN) cnt[i] = 0;
    if (i < NB * HD) pool[i] = 0.0;
    size_t g = (size_t)i * 4;
    int b = (int)(g / ((size_t)NN * FIN));
    size_t rem = g - (size_t)b * NN * FIN;
    int n = (int)(rem / FIN);
    int f = (int)(rem % FIN);
    float4 v = *(const float4*)&x[g];
    ushort4 o;
    o.x = f2bf(v.x); o.y = f2bf(v.y); o.z = f2bf(v.z); o.w = f2bf(v.w);
    *(ushort4*)&xb[((size_t)n * NB + b) * FIN + f] = o;
}

// ---------------- all 3 weight transpose-casts in one kernel ----------------
__global__ __launch_bounds__(256) void wcast_kernel(const float* __restrict__ W1,
                                                    const float* __restrict__ W2,
                                                    const float* __restrict__ W3,
                                                    ushort* __restrict__ w1t,
                                                    ushort* __restrict__ w2t,
                                                    ushort* __restrict__ w3t) {
    int bid = blockIdx.x;
    const float* W; ushort* WT; int K; int i;
    if (bid < 128)      { W = W1; WT = w1t; K = FIN; i = bid * 256 + threadIdx.x; }
    else if (bid < 384) { W = W2; WT = w2t; K = HD;  i = (bid - 128) * 256 + threadIdx.x; }
    else                { W = W3; WT = w3t; K = HD;  i = (bid - 384) * 256 + threadIdx.x; }
    int k = i >> 8, n = i & 255;
    WT[n * K + k] = f2bf(W[i]);
}

// ---------------- aggregation, 2-wide software-pipelined gather ----------------
// interleaved rows: row(n) = [b0 feats | b1 feats], RW elems.
template <int FEAT>
__global__ __launch_bounds__(256) void agg_kernel(const ushort* __restrict__ h,
                                                  const int2* __restrict__ edge2,
                                                  const int* __restrict__ rstart,
                                                  const float* __restrict__ dinv,
                                                  ushort* __restrict__ out) {
    constexpr int RW = NB * FEAT;             // 256 or 512 elems per row
    constexpr int EL = RW / 64;               // 4 or 8 elems per lane
    constexpr int NU = EL / 2;                // uints per lane
    using VecT = std::conditional_t<EL == 8, uint4, uint2>;
    union UV { VecT v; unsigned int u[NU]; };

    int wid = threadIdx.x >> 6;
    int l = threadIdx.x & 63;
    int n = blockIdx.x * 4 + wid;
    const ushort* hb = h + l * EL;            // lane-offset base
    float dn = dinv[n];
    float acc[EL];

    auto accum = [&](const UV& v, float w) {
#pragma unroll
        for (int k = 0; k < NU; ++k) {
            acc[2 * k]     += w * bf2f((ushort)(v.u[k] & 0xffff));
            acc[2 * k + 1] += w * bf2f((ushort)(v.u[k] >> 16));
        }
    };

    {   // self-loop term
        UV s; s.v = *(const VecT*)&hb[(size_t)n * RW];
        float w = dn * dn;
#pragma unroll
        for (int k = 0; k < NU; ++k) {
            acc[2 * k]     = w * bf2f((ushort)(s.u[k] & 0xffff));
            acc[2 * k + 1] = w * bf2f((ushort)(s.u[k] >> 16));
        }
    }

    int e0 = rstart[n], e1 = rstart[n + 1];
    int2 m0, m1, m2, m3;
    UV r0, r1;
    if (e0 + 0 < e1) m0 = edge2[e0 + 0];
    if (e0 + 1 < e1) m1 = edge2[e0 + 1];
    if (e0 + 2 < e1) m2 = edge2[e0 + 2];
    if (e0 + 3 < e1) m3 = edge2[e0 + 3];
    if (e0 + 0 < e1) r0.v = *(const VecT*)&hb[(size_t)m0.x * RW];
    if (e0 + 1 < e1) r1.v = *(const VecT*)&hb[(size_t)m1.x * RW];

    int e = e0;
    for (; e + 1 < e1; e += 2) {
        UV c0 = r0, c1 = r1;
        float w0 = __int_as_float(m0.y), w1 = __int_as_float(m1.y);
        m0 = m2; m1 = m3;
        if (e + 4 < e1) m2 = edge2[e + 4];
        if (e + 5 < e1) m3 = edge2[e + 5];
        if (e + 2 < e1) r0.v = *(const VecT*)&hb[(size_t)m0.x * RW];
        if (e + 3 < e1) r1.v = *(const VecT*)&hb[(size_t)m1.x * RW];
        accum(c0, w0);
        accum(c1, w1);
    }
    if (e < e1) accum(r0, __int_as_float(m0.y));

    UV o;
#pragma unroll
    for (int k = 0; k < NU; ++k)
        o.u[k] = (unsigned int)f2bf(acc[2 * k]) | ((unsigned int)f2bf(acc[2 * k + 1]) << 16);
    *(VecT*)&((ushort*)out)[(size_t)n * RW + l * EL] = o.v;
}

// ---------------- MFMA GEMM: C[MP,256] = relu(A[MP,K] @ BT[256,K]^T + bias), bf16
template <int K>
__global__ __launch_bounds__(256) void gemm_kernel(const ushort* __restrict__ A,
                                                   const ushort* __restrict__ BT,
                                                   const float* __restrict__ bias,
                                                   ushort* __restrict__ C) {
    const int BK = 64;
    __shared__ ushort As[128 * BK];   // 16KB, XOR-swizzled rows of 8 16B-chunks
    __shared__ ushort Bs[128 * BK];
    int t = threadIdx.x;
    int l = t & 63, w = t >> 6;
    int wr = w >> 1, wc = w & 1;
    size_t bm = (size_t)blockIdx.x * 128;
    int bn = blockIdx.y * 128;
    f32x4 acc[4][4] = {};
    for (int kt = 0; kt < K; kt += BK) {
        uint4 ra[4], rb[4];
#pragma unroll
        for (int i = 0; i < 4; ++i) {
            int c = i * 256 + t;           // chunk 0..1023
            int row = c >> 3, kc = c & 7;  // 8 chunks (16B) per row
            ra[i] = *(const uint4*)&A[(bm + row) * K + kt + kc * 8];
            rb[i] = *(const uint4*)&BT[(size_t)(bn + row) * K + kt + kc * 8];
        }
        __syncthreads();
#pragma unroll
        for (int i = 0; i < 4; ++i) {
            int c = i * 256 + t;
            int row = c >> 3, kc = c & 7;
            int sw = kc ^ (row & 7);
            *(uint4*)&As[row * 64 + sw * 8] = ra[i];
            *(uint4*)&Bs[row * 64 + sw * 8] = rb[i];
        }
        __syncthreads();
#pragma unroll
        for (int s = 0; s < 2; ++s) {
            bf16x8 af[4], bfr[4];
#pragma unroll
            for (int m = 0; m < 4; ++m) {
                int row = wr * 64 + m * 16 + (l & 15);
                int chunk = s * 4 + (l >> 4);
                af[m] = *(const bf16x8*)&As[row * 64 + (chunk ^ (row & 7)) * 8];
            }
#pragma unroll
            for (int n = 0; n < 4; ++n) {
                int row = wc * 64 + n * 16 + (l & 15);
                int chunk = s * 4 + (l >> 4);
                bfr[n] = *(const bf16x8*)&Bs[row * 64 + (chunk ^ (row & 7)) * 8];
            }
#pragma unroll
            for (int m = 0; m < 4; ++m)
#pragma unroll
                for (int n = 0; n < 4; ++n)
                    acc[m][n] = __builtin_amdgcn_mfma_f32_16x16x32_bf16(af[m], bfr[n], acc[m][n], 0, 0, 0);
        }
    }
    // epilogue: bias + relu + bf16 store. D layout: col=l&15, row=(l>>4)*4+j
#pragma unroll
    for (int m = 0; m < 4; ++m) {
#pragma unroll
        for (int n = 0; n < 4; ++n) {
            int col = bn + wc * 64 + n * 16 + (l & 15);
            float bv = bias[col];
#pragma unroll
            for (int j = 0; j < 4; ++j) {
                size_t row = bm + wr * 64 + m * 16 + (l >> 4) * 4 + j;
                float v = fmaxf(acc[m][n][j] + bv, 0.0f);
                C[row * HD + col] = f2bf(v);
            }
        }
    }
}

// ---------------- column sums for mean pool (bf16, interleaved rows) ----------------
__global__ __launch_bounds__(256) void colsum_kernel(const ushort* __restrict__ h, double* pool) {
    const int NCH = 32;                       // nodes per block; 625 blocks
    int n0 = blockIdx.x * NCH;
    int t = threadIdx.x;
    const unsigned int* hu = (const unsigned int*)h;
    int b = t >> 7;                            // elem g=2t: row parity
    int f0 = (2 * t) & 255;
    float s0 = 0.0f, s1 = 0.0f;
    for (int n = n0; n < n0 + NCH; ++n) {
        unsigned int u = hu[(size_t)n * (NB * HD / 2) + t];
        s0 += bf2f((ushort)(u & 0xffff));
        s1 += bf2f((ushort)(u >> 16));
    }
    atomicAdd(&pool[b * HD + f0], (double)s0);
    atomicAdd(&pool[b * HD + f0 + 1], (double)s1);
}

// ---------------- head: out[b] = mean_h . Wl + bl ----------------
__global__ __launch_bounds__(256) void head_kernel(const double* __restrict__ pool,
                                                   const float* __restrict__ Wl,
                                                   const float* __restrict__ bl,
                                                   float* __restrict__ out) {
    __shared__ double red[256];
    int f = threadIdx.x;
    for (int b = 0; b < NB; ++b) {
        double v = pool[b * HD + f] * (1.0 / NN) * (double)Wl[f];
        red[f] = v;
        __syncthreads();
        for (int off = 128; off; off >>= 1) {
            if (f < off) red[f] += red[f + off];
            __syncthreads();
        }
        if (f == 0) out[b] = (float)(red[0] + (double)bl[0]);
        __syncthreads();
    }
}

extern "C" void kernel_launch(void* const* d_in, const int* in_sizes, int n_in,
                              void* d_out, int out_size, void* d_ws, size_t ws_size,
                              hipStream_t stream) {
    const float* x  = (const float*)d_in[0];
    const int* eidx = (const int*)d_in[1];
    const float* W1 = (const float*)d_in[2];
    const float* b1 = (const float*)d_in[3];
    const float* W2 = (const float*)d_in[4];
    const float* b2 = (const float*)d_in[5];
    const float* W3 = (const float*)d_in[6];
    const float* b3 = (const float*)d_in[7];
    const float* Wl = (const float*)d_in[8];
    const float* bl = (const float*)d_in[9];
    float* out = (float*)d_out;

    const int* src = eidx;
    const int* dst = eidx + NE;

    // ---- workspace layout (bytes, 256B-aligned blocks) ----
    char* p = (char*)d_ws;
    auto alloc = [&](size_t bytes) { char* r = p; p += (bytes + 255) & ~(size_t)255; return r; };
    ushort* xb    = (ushort*)alloc((size_t)MP * FIN * 2);
    ushort* aggx  = (ushort*)alloc((size_t)MP * FIN * 2);
    ushort* bufA  = (ushort*)alloc((size_t)MP * HD * 2);
    ushort* bufB  = (ushort*)alloc((size_t)MP * HD * 2);
    ushort* w1t   = (ushort*)alloc((size_t)HD * FIN * 2);
    ushort* w2t   = (ushort*)alloc((size_t)HD * HD * 2);
    ushort* w3t   = (ushort*)alloc((size_t)HD * HD * 2);
    float*  dinv  = (float*)alloc(NN * 4);
    int2*   edge2 = (int2*)alloc((size_t)NE * 8);
    int*    cnt   = (int*)alloc(NN * 4);
    int*    rstart= (int*)alloc((NN + 1) * 4);
    double* pool  = (double*)alloc(NB * HD * 8);

    // castx also zeroes cnt/pool (runs before count/colsum-users)
    castx_kernel<<<(NB * NN * FIN / 4 + 255) / 256, 256, 0, stream>>>(x, xb, cnt, pool);
    count_kernel<<<(NE + 255) / 256, 256, 0, stream>>>(dst, cnt);
    scan_kernel<<<1, 1024, 0, stream>>>(cnt, rstart, dinv);
    bucket_kernel<<<(NE + 255) / 256, 256, 0, stream>>>(src, dst, cnt, edge2, dinv);
    wcast_kernel<<<640, 256, 0, stream>>>(W1, W2, W3, w1t, w2t, w3t);

    dim3 agrid(NN / 4, 1);
    dim3 ggrid(MP / 128, HD / 128);

    // layer 1: h1 = relu(agg(x) @ W1 + b1)
    agg_kernel<FIN><<<agrid, 256, 0, stream>>>(xb, edge2, rstart, dinv, aggx);
    gemm_kernel<FIN><<<ggrid, 256, 0, stream>>>(aggx, w1t, b1, bufA);
    // layer 2
    agg_kernel<HD><<<agrid, 256, 0, stream>>>(bufA, edge2, rstart, dinv, bufB);
    gemm_kernel<HD><<<ggrid, 256, 0, stream>>>(bufB, w2t, b2, bufA);
    // layer 3
    agg_kernel<HD><<<agrid, 256, 0, stream>>>(bufA, edge2, rstart, dinv, bufB);
    gemm_kernel<HD><<<ggrid, 256, 0, stream>>>(bufB, w3t, b3, bufA);

    // mean pool + head
    colsum_kernel<<<NN / 32, 256, 0, stream>>>(bufA, pool);
    head_kernel<<<1, 256, 0, stream>>>(pool, Wl, bl, out);
}

// Round 5
// 382.141 us; speedup vs baseline: 2.1501x; 1.1177x over previous
//
#include <hip/hip_runtime.h>
#include <hip/hip_bf16.h>
#include <type_traits>

#define NN 20000      // nodes
#define NE 320000     // edges
#define HD 256        // hidden dim
#define NB 2          // batch
#define FIN 128
#define MP 40064      // NB*NN padded to multiple of 128 (313*128)
#define SB 79         // scan blocks = ceil(NN/256)

typedef __attribute__((ext_vector_type(8))) short bf16x8;
typedef __attribute__((ext_vector_type(4))) float f32x4;

__device__ inline float bf2f(ushort u) {
    union { unsigned int i; float f; } c; c.i = ((unsigned int)u) << 16; return c.f;
}
__device__ inline ushort f2bf(float f) {
    __hip_bfloat16 h = __float2bfloat16(f);
    return *reinterpret_cast<ushort*>(&h);
}

// ---------------- count incoming edges per dst ----------------
__global__ __launch_bounds__(256) void count_kernel(const int* __restrict__ dst, int* cnt) {
    int e = blockIdx.x * 256 + threadIdx.x;
    if (e < NE) atomicAdd(&cnt[dst[e]], 1);
}

// ---------------- scan stage 1: per-block sums + dinv ----------------
__global__ __launch_bounds__(256) void scan_blk_kernel(const int* __restrict__ cnt,
                                                       int* __restrict__ bsum,
                                                       float* __restrict__ dinv) {
    __shared__ int s[256];
    int t = threadIdx.x, b = blockIdx.x;
    int n = b * 256 + t;
    int c = (n < NN) ? cnt[n] : 0;
    if (n < NN) dinv[n] = rsqrtf(1.0f + (float)c);
    s[t] = c;
    __syncthreads();
    for (int off = 128; off; off >>= 1) {
        if (t < off) s[t] += s[t + off];
        __syncthreads();
    }
    if (t == 0) bsum[b] = s[0];
}

// ---------------- scan stage 2: block offset + intra-block exclusive scan ----------------
__global__ __launch_bounds__(256) void scan_fin_kernel(const int* __restrict__ bsum,
                                                       int* __restrict__ cnt,
                                                       int* __restrict__ rstart) {
    __shared__ int sb[128];
    __shared__ int s[256];
    int t = threadIdx.x, b = blockIdx.x;
    if (t < 128) sb[t] = (t < SB) ? bsum[t] : 0;
    __syncthreads();
    for (int off = 1; off < 128; off <<= 1) {
        int v = (t < 128 && t >= off) ? sb[t - off] : 0;
        __syncthreads();
        if (t < 128) sb[t] += v;
        __syncthreads();
    }
    int boff = (b == 0) ? 0 : sb[b - 1];
    int n = b * 256 + t;
    int c = (n < NN) ? cnt[n] : 0;
    s[t] = c;
    __syncthreads();
    for (int off = 1; off < 256; off <<= 1) {
        int v = (t >= off) ? s[t - off] : 0;
        __syncthreads();
        s[t] += v;
        __syncthreads();
    }
    int excl = s[t] - c + boff;
    if (n < NN) { rstart[n] = excl; cnt[n] = excl; }   // cnt becomes bucket cursor
    if (b == 0 && t == 0) rstart[NN] = NE;
}

// ---------------- bucket edges by dst, precompute weights ----------------
__global__ __launch_bounds__(256) void bucket_kernel(const int* __restrict__ src,
                                                     const int* __restrict__ dst,
                                                     int* cursor, int2* edge2,
                                                     const float* __restrict__ dinv) {
    int e = blockIdx.x * 256 + threadIdx.x;
    if (e >= NE) return;
    int s = src[e], d = dst[e];
    int pos = atomicAdd(&cursor[d], 1);
    float w = dinv[s] * dinv[d];
    edge2[pos] = make_int2(s, __float_as_int(w));
}

// ---------------- fused: cast x -> bf16 interleaved, zero cnt/pool, wcast x3 ----------------
// blocks [0,5000): castx ; [5000,5128): W1 ; [5128,5384): W2 ; [5384,5640): W3
__global__ __launch_bounds__(256) void prep_kernel(const float* __restrict__ x,
                                                   ushort* __restrict__ xb,
                                                   int* cnt, double* pool,
                                                   const float* __restrict__ W1,
                                                   const float* __restrict__ W2,
                                                   const float* __restrict__ W3,
                                                   ushort* __restrict__ w1t,
                                                   ushort* __restrict__ w2t,
                                                   ushort* __restrict__ w3t) {
    int bid = blockIdx.x;
    int t = threadIdx.x;
    if (bid < 5000) {
        int i = bid * 256 + t;                // quad index, < 1,280,000
        if (i < NN) cnt[i] = 0;
        if (i < NB * HD) pool[i] = 0.0;
        size_t g = (size_t)i * 4;
        int b = (i >= (NN * FIN / 4));        // NN*FIN/4 = 640000
        size_t rem = g - (size_t)b * NN * FIN;
        int n = (int)(rem >> 7);              // / FIN
        int f = (int)(rem & (FIN - 1));
        float4 v = *(const float4*)&x[g];
        ushort4 o;
        o.x = f2bf(v.x); o.y = f2bf(v.y); o.z = f2bf(v.z); o.w = f2bf(v.w);
        *(ushort4*)&xb[((size_t)n * NB + b) * FIN + f] = o;
    } else {
        const float* W; ushort* WT; int K; int i;
        if (bid < 5128)      { W = W1; WT = w1t; K = FIN; i = (bid - 5000) * 256 + t; }
        else if (bid < 5384) { W = W2; WT = w2t; K = HD;  i = (bid - 5128) * 256 + t; }
        else                 { W = W3; WT = w3t; K = HD;  i = (bid - 5384) * 256 + t; }
        int k = i >> 8, n = i & 255;
        WT[n * K + k] = f2bf(W[i]);
    }
}

// ---------------- aggregation, 8-deep row pipeline ----------------
// interleaved rows: row(n) = [b0 feats | b1 feats], RW elems. One wave per node.
template <int FEAT>
__global__ __launch_bounds__(256) void agg_kernel(const ushort* __restrict__ h,
                                                  const int2* __restrict__ edge2,
                                                  const int* __restrict__ rstart,
                                                  const float* __restrict__ dinv,
                                                  ushort* __restrict__ out) {
    constexpr int RW = NB * FEAT;             // 256 or 512 elems per row
    constexpr int EL = RW / 64;               // 4 or 8 elems per lane
    constexpr int NU = EL / 2;                // uints per lane
    using VecT = std::conditional_t<EL == 8, uint4, uint2>;
    union UV { VecT v; unsigned int u[NU]; };

    int wid = threadIdx.x >> 6;
    int l = threadIdx.x & 63;
    int n = blockIdx.x * 4 + wid;
    const ushort* hb = h + l * EL;            // lane-offset base
    float dn = dinv[n];
    float acc[EL];

    auto accum = [&](const UV& v, float w) {
#pragma unroll
        for (int k = 0; k < NU; ++k) {
            acc[2 * k]     += w * bf2f((ushort)(v.u[k] & 0xffff));
            acc[2 * k + 1] += w * bf2f((ushort)(v.u[k] >> 16));
        }
    };

    {   // self-loop term
        UV s; s.v = *(const VecT*)&hb[(size_t)n * RW];
        float w = dn * dn;
#pragma unroll
        for (int k = 0; k < NU; ++k) {
            acc[2 * k]     = w * bf2f((ushort)(s.u[k] & 0xffff));
            acc[2 * k + 1] = w * bf2f((ushort)(s.u[k] >> 16));
        }
    }

    int e0 = rstart[n], e1 = rstart[n + 1];
    int deg = e1 - e0;                        // wave-uniform
    const int2* ep = edge2 + e0;

    int2 m[12];
    UV r[8];
#pragma unroll
    for (int i = 0; i < 12; ++i) if (i < deg) m[i] = ep[i];
#pragma unroll
    for (int i = 0; i < 8; ++i) if (i < deg) r[i].v = *(const VecT*)&hb[(size_t)m[i].x * RW];

    int e = 0;
    for (; e + 4 <= deg; e += 4) {
#pragma unroll
        for (int i = 0; i < 4; ++i) accum(r[i], __int_as_float(m[i].y));
#pragma unroll
        for (int i = 0; i < 8; ++i) m[i] = m[i + 4];
#pragma unroll
        for (int i = 0; i < 4; ++i) r[i] = r[i + 4];
#pragma unroll
        for (int i = 0; i < 4; ++i) if (e + 12 + i < deg) m[8 + i] = ep[e + 12 + i];
#pragma unroll
        for (int i = 4; i < 8; ++i) if (e + 4 + i < deg) r[i].v = *(const VecT*)&hb[(size_t)m[i].x * RW];
    }
#pragma unroll
    for (int i = 0; i < 3; ++i) if (e + i < deg) accum(r[i], __int_as_float(m[i].y));

    UV o;
#pragma unroll
    for (int k = 0; k < NU; ++k)
        o.u[k] = (unsigned int)f2bf(acc[2 * k]) | ((unsigned int)f2bf(acc[2 * k + 1]) << 16);
    *(VecT*)&((ushort*)out)[(size_t)n * RW + l * EL] = o.v;
}

// ---------------- MFMA GEMM: C[MP,256] = relu(A[MP,K] @ BT[256,K]^T + bias), bf16
template <int K>
__global__ __launch_bounds__(256) void gemm_kernel(const ushort* __restrict__ A,
                                                   const ushort* __restrict__ BT,
                                                   const float* __restrict__ bias,
                                                   ushort* __restrict__ C) {
    const int BK = 64;
    __shared__ ushort As[128 * BK];   // 16KB, XOR-swizzled rows of 8 16B-chunks
    __shared__ ushort Bs[128 * BK];
    int t = threadIdx.x;
    int l = t & 63, w = t >> 6;
    int wr = w >> 1, wc = w & 1;
    size_t bm = (size_t)blockIdx.x * 128;
    int bn = blockIdx.y * 128;
    f32x4 acc[4][4] = {};
    for (int kt = 0; kt < K; kt += BK) {
        uint4 ra[4], rb[4];
#pragma unroll
        for (int i = 0; i < 4; ++i) {
            int c = i * 256 + t;           // chunk 0..1023
            int row = c >> 3, kc = c & 7;  // 8 chunks (16B) per row
            ra[i] = *(const uint4*)&A[(bm + row) * K + kt + kc * 8];
            rb[i] = *(const uint4*)&BT[(size_t)(bn + row) * K + kt + kc * 8];
        }
        __syncthreads();
#pragma unroll
        for (int i = 0; i < 4; ++i) {
            int c = i * 256 + t;
            int row = c >> 3, kc = c & 7;
            int sw = kc ^ (row & 7);
            *(uint4*)&As[row * 64 + sw * 8] = ra[i];
            *(uint4*)&Bs[row * 64 + sw * 8] = rb[i];
        }
        __syncthreads();
#pragma unroll
        for (int s = 0; s < 2; ++s) {
            bf16x8 af[4], bfr[4];
#pragma unroll
            for (int m = 0; m < 4; ++m) {
                int row = wr * 64 + m * 16 + (l & 15);
                int chunk = s * 4 + (l >> 4);
                af[m] = *(const bf16x8*)&As[row * 64 + (chunk ^ (row & 7)) * 8];
            }
#pragma unroll
            for (int n = 0; n < 4; ++n) {
                int row = wc * 64 + n * 16 + (l & 15);
                int chunk = s * 4 + (l >> 4);
                bfr[n] = *(const bf16x8*)&Bs[row * 64 + (chunk ^ (row & 7)) * 8];
            }
#pragma unroll
            for (int m = 0; m < 4; ++m)
#pragma unroll
                for (int n = 0; n < 4; ++n)
                    acc[m][n] = __builtin_amdgcn_mfma_f32_16x16x32_bf16(af[m], bfr[n], acc[m][n], 0, 0, 0);
        }
    }
    // epilogue: bias + relu + bf16 store. D layout: col=l&15, row=(l>>4)*4+j
#pragma unroll
    for (int m = 0; m < 4; ++m) {
#pragma unroll
        for (int n = 0; n < 4; ++n) {
            int col = bn + wc * 64 + n * 16 + (l & 15);
            float bv = bias[col];
#pragma unroll
            for (int j = 0; j < 4; ++j) {
                size_t row = bm + wr * 64 + m * 16 + (l >> 4) * 4 + j;
                float v = fmaxf(acc[m][n][j] + bv, 0.0f);
                C[row * HD + col] = f2bf(v);
            }
        }
    }
}

// ---------------- column sums for mean pool (bf16, interleaved rows) ----------------
__global__ __launch_bounds__(256) void colsum_kernel(const ushort* __restrict__ h, double* pool) {
    const int NCH = 32;                       // nodes per block; 625 blocks
    int n0 = blockIdx.x * NCH;
    int t = threadIdx.x;
    const unsigned int* hu = (const unsigned int*)h;
    int b = t >> 7;                            // elem g=2t: row parity
    int f0 = (2 * t) & 255;
    float s0 = 0.0f, s1 = 0.0f;
    for (int n = n0; n < n0 + NCH; ++n) {
        unsigned int u = hu[(size_t)n * (NB * HD / 2) + t];
        s0 += bf2f((ushort)(u & 0xffff));
        s1 += bf2f((ushort)(u >> 16));
    }
    atomicAdd(&pool[b * HD + f0], (double)s0);
    atomicAdd(&pool[b * HD + f0 + 1], (double)s1);
}

// ---------------- head: out[b] = mean_h . Wl + bl ----------------
__global__ __launch_bounds__(256) void head_kernel(const double* __restrict__ pool,
                                                   const float* __restrict__ Wl,
                                                   const float* __restrict__ bl,
                                                   float* __restrict__ out) {
    __shared__ double red[256];
    int f = threadIdx.x;
    for (int b = 0; b < NB; ++b) {
        double v = pool[b * HD + f] * (1.0 / NN) * (double)Wl[f];
        red[f] = v;
        __syncthreads();
        for (int off = 128; off; off >>= 1) {
            if (f < off) red[f] += red[f + off];
            __syncthreads();
        }
        if (f == 0) out[b] = (float)(red[0] + (double)bl[0]);
        __syncthreads();
    }
}

extern "C" void kernel_launch(void* const* d_in, const int* in_sizes, int n_in,
                              void* d_out, int out_size, void* d_ws, size_t ws_size,
                              hipStream_t stream) {
    const float* x  = (const float*)d_in[0];
    const int* eidx = (const int*)d_in[1];
    const float* W1 = (const float*)d_in[2];
    const float* b1 = (const float*)d_in[3];
    const float* W2 = (const float*)d_in[4];
    const float* b2 = (const float*)d_in[5];
    const float* W3 = (const float*)d_in[6];
    const float* b3 = (const float*)d_in[7];
    const float* Wl = (const float*)d_in[8];
    const float* bl = (const float*)d_in[9];
    float* out = (float*)d_out;

    const int* src = eidx;
    const int* dst = eidx + NE;

    // ---- workspace layout (bytes, 256B-aligned blocks) ----
    char* p = (char*)d_ws;
    auto alloc = [&](size_t bytes) { char* r = p; p += (bytes + 255) & ~(size_t)255; return r; };
    ushort* xb    = (ushort*)alloc((size_t)MP * FIN * 2);
    ushort* aggx  = (ushort*)alloc((size_t)MP * FIN * 2);
    ushort* bufA  = (ushort*)alloc((size_t)MP * HD * 2);
    ushort* bufB  = (ushort*)alloc((size_t)MP * HD * 2);
    ushort* w1t   = (ushort*)alloc((size_t)HD * FIN * 2);
    ushort* w2t   = (ushort*)alloc((size_t)HD * HD * 2);
    ushort* w3t   = (ushort*)alloc((size_t)HD * HD * 2);
    float*  dinv  = (float*)alloc(NN * 4);
    int2*   edge2 = (int2*)alloc((size_t)NE * 8);
    int*    cnt   = (int*)alloc(NN * 4);
    int*    rstart= (int*)alloc((NN + 1) * 4);
    int*    bsum  = (int*)alloc(SB * 4);
    double* pool  = (double*)alloc(NB * HD * 8);

    // prep: castx (+ zero cnt/pool) + all weight casts
    prep_kernel<<<5640, 256, 0, stream>>>(x, xb, cnt, pool, W1, W2, W3, w1t, w2t, w3t);
    count_kernel<<<(NE + 255) / 256, 256, 0, stream>>>(dst, cnt);
    scan_blk_kernel<<<SB, 256, 0, stream>>>(cnt, bsum, dinv);
    scan_fin_kernel<<<SB, 256, 0, stream>>>(bsum, cnt, rstart);
    bucket_kernel<<<(NE + 255) / 256, 256, 0, stream>>>(src, dst, cnt, edge2, dinv);

    dim3 agrid(NN / 4, 1);
    dim3 ggrid(MP / 128, HD / 128);

    // layer 1: h1 = relu(agg(x) @ W1 + b1)
    agg_kernel<FIN><<<agrid, 256, 0, stream>>>(xb, edge2, rstart, dinv, aggx);
    gemm_kernel<FIN><<<ggrid, 256, 0, stream>>>(aggx, w1t, b1, bufA);
    // layer 2
    agg_kernel<HD><<<agrid, 256, 0, stream>>>(bufA, edge2, rstart, dinv, bufB);
    gemm_kernel<HD><<<ggrid, 256, 0, stream>>>(bufB, w2t, b2, bufA);
    // layer 3
    agg_kernel<HD><<<agrid, 256, 0, stream>>>(bufA, edge2, rstart, dinv, bufB);
    gemm_kernel<HD><<<ggrid, 256, 0, stream>>>(bufB, w3t, b3, bufA);

    // mean pool + head
    colsum_kernel<<<NN / 32, 256, 0, stream>>>(bufA, pool);
    head_kernel<<<1, 256, 0, stream>>>(pool, Wl, bl, out);
}

// Round 6
// 343.829 us; speedup vs baseline: 2.3897x; 1.1114x over previous
//
#include <hip/hip_runtime.h>
#include <hip/hip_bf16.h>
#include <type_traits>

#define NN 20000      // nodes
#define NE 320000     // edges
#define HD 256        // hidden dim
#define NB 2          // batch
#define FIN 128
#define MP 40064      // NB*NN padded to multiple of 128 (313*128)
#define SB 79         // scan blocks = ceil(NN/256)

typedef __attribute__((ext_vector_type(8))) short bf16x8;
typedef __attribute__((ext_vector_type(4))) float f32x4;

__device__ inline float bf2f(ushort u) {
    union { unsigned int i; float f; } c; c.i = ((unsigned int)u) << 16; return c.f;
}
__device__ inline ushort f2bf(float f) {
    __hip_bfloat16 h = __float2bfloat16(f);
    return *reinterpret_cast<ushort*>(&h);
}

// ---------------- count incoming edges per dst ----------------
__global__ __launch_bounds__(256) void count_kernel(const int* __restrict__ dst, int* cnt) {
    int e = blockIdx.x * 256 + threadIdx.x;
    if (e < NE) atomicAdd(&cnt[dst[e]], 1);
}

// ---------------- scan stage 1: per-block sums + dinv ----------------
__global__ __launch_bounds__(256) void scan_blk_kernel(const int* __restrict__ cnt,
                                                       int* __restrict__ bsum,
                                                       float* __restrict__ dinv) {
    __shared__ int s[256];
    int t = threadIdx.x, b = blockIdx.x;
    int n = b * 256 + t;
    int c = (n < NN) ? cnt[n] : 0;
    if (n < NN) dinv[n] = rsqrtf(1.0f + (float)c);
    s[t] = c;
    __syncthreads();
    for (int off = 128; off; off >>= 1) {
        if (t < off) s[t] += s[t + off];
        __syncthreads();
    }
    if (t == 0) bsum[b] = s[0];
}

// ---------------- scan stage 2: block offset + intra-block exclusive scan ----------------
__global__ __launch_bounds__(256) void scan_fin_kernel(const int* __restrict__ bsum,
                                                       int* __restrict__ cnt,
                                                       int* __restrict__ rstart) {
    __shared__ int sb[128];
    __shared__ int s[256];
    int t = threadIdx.x, b = blockIdx.x;
    if (t < 128) sb[t] = (t < SB) ? bsum[t] : 0;
    __syncthreads();
    for (int off = 1; off < 128; off <<= 1) {
        int v = (t < 128 && t >= off) ? sb[t - off] : 0;
        __syncthreads();
        if (t < 128) sb[t] += v;
        __syncthreads();
    }
    int boff = (b == 0) ? 0 : sb[b - 1];
    int n = b * 256 + t;
    int c = (n < NN) ? cnt[n] : 0;
    s[t] = c;
    __syncthreads();
    for (int off = 1; off < 256; off <<= 1) {
        int v = (t >= off) ? s[t - off] : 0;
        __syncthreads();
        s[t] += v;
        __syncthreads();
    }
    int excl = s[t] - c + boff;
    if (n < NN) { rstart[n] = excl; cnt[n] = excl; }   // cnt becomes bucket cursor
    if (b == 0 && t == 0) rstart[NN] = NE;
}

// ---------------- bucket edges by dst, precompute weights ----------------
__global__ __launch_bounds__(256) void bucket_kernel(const int* __restrict__ src,
                                                     const int* __restrict__ dst,
                                                     int* cursor, int2* edge2,
                                                     const float* __restrict__ dinv) {
    int e = blockIdx.x * 256 + threadIdx.x;
    if (e >= NE) return;
    int s = src[e], d = dst[e];
    int pos = atomicAdd(&cursor[d], 1);
    float w = dinv[s] * dinv[d];
    edge2[pos] = make_int2(s, __float_as_int(w));
}

// ---------------- fused: cast x -> bf16 interleaved, zero cnt/pool, wcast x3 ----------------
// blocks [0,5000): castx ; [5000,5128): W1 ; [5128,5384): W2 ; [5384,5640): W3
__global__ __launch_bounds__(256) void prep_kernel(const float* __restrict__ x,
                                                   ushort* __restrict__ xb,
                                                   int* cnt, double* pool,
                                                   const float* __restrict__ W1,
                                                   const float* __restrict__ W2,
                                                   const float* __restrict__ W3,
                                                   ushort* __restrict__ w1t,
                                                   ushort* __restrict__ w2t,
                                                   ushort* __restrict__ w3t) {
    int bid = blockIdx.x;
    int t = threadIdx.x;
    if (bid < 5000) {
        int i = bid * 256 + t;                // quad index, < 1,280,000
        if (i < NN) cnt[i] = 0;
        if (i < NB * HD) pool[i] = 0.0;
        size_t g = (size_t)i * 4;
        int b = (i >= (NN * FIN / 4));        // NN*FIN/4 = 640000
        size_t rem = g - (size_t)b * NN * FIN;
        int n = (int)(rem >> 7);              // / FIN
        int f = (int)(rem & (FIN - 1));
        float4 v = *(const float4*)&x[g];
        ushort4 o;
        o.x = f2bf(v.x); o.y = f2bf(v.y); o.z = f2bf(v.z); o.w = f2bf(v.w);
        *(ushort4*)&xb[((size_t)n * NB + b) * FIN + f] = o;
    } else {
        const float* W; ushort* WT; int K; int i;
        if (bid < 5128)      { W = W1; WT = w1t; K = FIN; i = (bid - 5000) * 256 + t; }
        else if (bid < 5384) { W = W2; WT = w2t; K = HD;  i = (bid - 5128) * 256 + t; }
        else                 { W = W3; WT = w3t; K = HD;  i = (bid - 5384) * 256 + t; }
        int k = i >> 8, n = i & 255;
        WT[n * K + k] = f2bf(W[i]);
    }
}

// ================= fused layer: agg (gather into LDS) + MFMA GEMM + bias + relu =================
// h: prev activations, interleaved rows: node n -> [b0 K-feats | b1 K-feats] (RW = NB*K elems).
// Viewed as GEMM A: A-row (n*NB+b) x K. Block computes 64 A-rows (32 nodes) x 256 cols.
// BT: weights [HD][K] bf16. C: [MP][HD] bf16 interleaved rows.
template <int K>
__global__ __launch_bounds__(512, 4) void fused_kernel(const ushort* __restrict__ h,
                                                       const ushort* __restrict__ BT,
                                                       const float* __restrict__ bias,
                                                       const int2* __restrict__ edge2,
                                                       const int* __restrict__ rstart,
                                                       const float* __restrict__ dinv,
                                                       ushort* __restrict__ C) {
    constexpr int RW = NB * K;            // 256 or 512 elems per node row
    constexpr int EL = RW / 64;           // 4 or 8 elems per lane
    constexpr int NU = EL / 2;            // uints per lane
    using VecT = std::conditional_t<EL == 8, uint4, uint2>;
    union UV { VecT v; unsigned int u[NU]; };

    __shared__ ushort As[64 * K];         // swizzled: addr = row*K + ((chunk ^ (row&7))<<3)
    __shared__ ushort Bs[256 * 64];       // swizzled per k-tile

    int t = threadIdx.x;
    int w = t >> 6, l = t & 63;
    int n0 = blockIdx.x * 32;
    const ushort* hb = h + l * EL;        // lane-offset base

    // ---------- phase 1: gather+agg 4 nodes per wave, write bf16 to As ----------
    for (int mi = 0; mi < 4; ++mi) {
        int mloc = w * 4 + mi;            // 0..31
        int n = n0 + mloc;
        float acc[EL];
#pragma unroll
        for (int k = 0; k < EL; ++k) acc[k] = 0.0f;

        if (n < NN) {
            float dn = dinv[n];
            {   // self-loop
                UV s; s.v = *(const VecT*)&hb[(size_t)n * RW];
                float ws = dn * dn;
#pragma unroll
                for (int k = 0; k < NU; ++k) {
                    acc[2 * k]     += ws * bf2f((ushort)(s.u[k] & 0xffff));
                    acc[2 * k + 1] += ws * bf2f((ushort)(s.u[k] >> 16));
                }
            }
            int e0 = rstart[n], e1 = rstart[n + 1];
            int deg = e1 - e0;            // wave-uniform
            const int2* ep = edge2 + e0;
            int2 mt[12];
            UV r[8];
#pragma unroll
            for (int i = 0; i < 12; ++i) if (i < deg) mt[i] = ep[i];
#pragma unroll
            for (int i = 0; i < 8; ++i) if (i < deg) r[i].v = *(const VecT*)&hb[(size_t)mt[i].x * RW];

            int e = 0;
            for (; e + 4 <= deg; e += 4) {
#pragma unroll
                for (int i = 0; i < 4; ++i) {
                    float ww = __int_as_float(mt[i].y);
#pragma unroll
                    for (int k = 0; k < NU; ++k) {
                        acc[2 * k]     += ww * bf2f((ushort)(r[i].u[k] & 0xffff));
                        acc[2 * k + 1] += ww * bf2f((ushort)(r[i].u[k] >> 16));
                    }
                }
#pragma unroll
                for (int i = 0; i < 8; ++i) mt[i] = mt[i + 4];
#pragma unroll
                for (int i = 0; i < 4; ++i) r[i] = r[i + 4];
#pragma unroll
                for (int i = 0; i < 4; ++i) if (e + 12 + i < deg) mt[8 + i] = ep[e + 12 + i];
#pragma unroll
                for (int i = 4; i < 8; ++i) if (e + 4 + i < deg) r[i].v = *(const VecT*)&hb[(size_t)mt[i].x * RW];
            }
#pragma unroll
            for (int i = 0; i < 3; ++i) {
                if (e + i < deg) {
                    float ww = __int_as_float(mt[i].y);
#pragma unroll
                    for (int k = 0; k < NU; ++k) {
                        acc[2 * k]     += ww * bf2f((ushort)(r[i].u[k] & 0xffff));
                        acc[2 * k + 1] += ww * bf2f((ushort)(r[i].u[k] >> 16));
                    }
                }
            }
        }

        // pack to bf16 and write swizzled As. A-row = 2*mloc + (l>=32); full-row chunk idx from lane.
        int arow = 2 * mloc + (l >> 5);
        if constexpr (EL == 8) {
            UV o;
#pragma unroll
            for (int k = 0; k < NU; ++k)
                o.u[k] = (unsigned int)f2bf(acc[2 * k]) | ((unsigned int)f2bf(acc[2 * k + 1]) << 16);
            *(uint4*)&As[arow * K + (((l & 31) ^ (arow & 7)) << 3)] = o.v;
        } else {
            UV o;
#pragma unroll
            for (int k = 0; k < NU; ++k)
                o.u[k] = (unsigned int)f2bf(acc[2 * k]) | ((unsigned int)f2bf(acc[2 * k + 1]) << 16);
            *(uint2*)&As[arow * K + ((((l & 31) >> 1) ^ (arow & 7)) << 3) + (l & 1) * 4] = o.v;
        }
    }

    // ---------- phase 2: MFMA over staged As, Bs staged per 64-k tile ----------
    int wr = w >> 2, wc = w & 3;          // 2 x 4 wave grid; wave tile 32 x 64
    f32x4 acc2[2][4] = {};
    constexpr int NKT = K / 64;
    for (int kt = 0; kt < NKT; ++kt) {
        if (kt > 0) __syncthreads();      // prior MFMA reads of Bs done
#pragma unroll
        for (int i = 0; i < 4; ++i) {
            int c = i * 512 + t;          // 2048 16B-chunks: 256 rows x 8
            int row = c >> 3, kc = c & 7;
            uint4 v = *(const uint4*)&BT[(size_t)row * K + kt * 64 + kc * 8];
            *(uint4*)&Bs[row * 64 + ((kc ^ (row & 7)) << 3)] = v;
        }
        __syncthreads();                  // publishes Bs (and As on first iter)
#pragma unroll
        for (int s = 0; s < 2; ++s) {
            bf16x8 af[2], bfr[4];
#pragma unroll
            for (int m = 0; m < 2; ++m) {
                int row = wr * 32 + m * 16 + (l & 15);
                int chunk = kt * 8 + s * 4 + (l >> 4);
                af[m] = *(const bf16x8*)&As[row * K + ((chunk ^ (row & 7)) << 3)];
            }
#pragma unroll
            for (int nn = 0; nn < 4; ++nn) {
                int row = wc * 64 + nn * 16 + (l & 15);
                int chunk = s * 4 + (l >> 4);
                bfr[nn] = *(const bf16x8*)&Bs[row * 64 + ((chunk ^ (row & 7)) << 3)];
            }
#pragma unroll
            for (int m = 0; m < 2; ++m)
#pragma unroll
                for (int nn = 0; nn < 4; ++nn)
                    acc2[m][nn] = __builtin_amdgcn_mfma_f32_16x16x32_bf16(af[m], bfr[nn], acc2[m][nn], 0, 0, 0);
        }
    }

    // ---------- epilogue: bias + relu + bf16 store ----------
    size_t bm = (size_t)blockIdx.x * 64;
#pragma unroll
    for (int m = 0; m < 2; ++m) {
#pragma unroll
        for (int nn = 0; nn < 4; ++nn) {
            int col = wc * 64 + nn * 16 + (l & 15);
            float bv = bias[col];
#pragma unroll
            for (int j = 0; j < 4; ++j) {
                size_t row = bm + wr * 32 + m * 16 + (l >> 4) * 4 + j;
                float v = fmaxf(acc2[m][nn][j] + bv, 0.0f);
                C[row * HD + col] = f2bf(v);
            }
        }
    }
}

// ---------------- column sums for mean pool (bf16, interleaved rows) ----------------
__global__ __launch_bounds__(256) void colsum_kernel(const ushort* __restrict__ h, double* pool) {
    const int NCH = 32;                       // nodes per block; 625 blocks
    int n0 = blockIdx.x * NCH;
    int t = threadIdx.x;
    const unsigned int* hu = (const unsigned int*)h;
    int b = t >> 7;                            // elem g=2t: row parity
    int f0 = (2 * t) & 255;
    float s0 = 0.0f, s1 = 0.0f;
    for (int n = n0; n < n0 + NCH; ++n) {
        unsigned int u = hu[(size_t)n * (NB * HD / 2) + t];
        s0 += bf2f((ushort)(u & 0xffff));
        s1 += bf2f((ushort)(u >> 16));
    }
    atomicAdd(&pool[b * HD + f0], (double)s0);
    atomicAdd(&pool[b * HD + f0 + 1], (double)s1);
}

// ---------------- head: out[b] = mean_h . Wl + bl ----------------
__global__ __launch_bounds__(256) void head_kernel(const double* __restrict__ pool,
                                                   const float* __restrict__ Wl,
                                                   const float* __restrict__ bl,
                                                   float* __restrict__ out) {
    __shared__ double red[256];
    int f = threadIdx.x;
    for (int b = 0; b < NB; ++b) {
        double v = pool[b * HD + f] * (1.0 / NN) * (double)Wl[f];
        red[f] = v;
        __syncthreads();
        for (int off = 128; off; off >>= 1) {
            if (f < off) red[f] += red[f + off];
            __syncthreads();
        }
        if (f == 0) out[b] = (float)(red[0] + (double)bl[0]);
        __syncthreads();
    }
}

extern "C" void kernel_launch(void* const* d_in, const int* in_sizes, int n_in,
                              void* d_out, int out_size, void* d_ws, size_t ws_size,
                              hipStream_t stream) {
    const float* x  = (const float*)d_in[0];
    const int* eidx = (const int*)d_in[1];
    const float* W1 = (const float*)d_in[2];
    const float* b1 = (const float*)d_in[3];
    const float* W2 = (const float*)d_in[4];
    const float* b2 = (const float*)d_in[5];
    const float* W3 = (const float*)d_in[6];
    const float* b3 = (const float*)d_in[7];
    const float* Wl = (const float*)d_in[8];
    const float* bl = (const float*)d_in[9];
    float* out = (float*)d_out;

    const int* src = eidx;
    const int* dst = eidx + NE;

    // ---- workspace layout (bytes, 256B-aligned blocks) ----
    char* p = (char*)d_ws;
    auto alloc = [&](size_t bytes) { char* r = p; p += (bytes + 255) & ~(size_t)255; return r; };
    ushort* xb    = (ushort*)alloc((size_t)MP * FIN * 2);
    ushort* bufA  = (ushort*)alloc((size_t)MP * HD * 2);
    ushort* bufB  = (ushort*)alloc((size_t)MP * HD * 2);
    ushort* w1t   = (ushort*)alloc((size_t)HD * FIN * 2);
    ushort* w2t   = (ushort*)alloc((size_t)HD * HD * 2);
    ushort* w3t   = (ushort*)alloc((size_t)HD * HD * 2);
    float*  dinv  = (float*)alloc(NN * 4);
    int2*   edge2 = (int2*)alloc((size_t)NE * 8);
    int*    cnt   = (int*)alloc(NN * 4);
    int*    rstart= (int*)alloc((NN + 1) * 4);
    int*    bsum  = (int*)alloc(SB * 4);
    double* pool  = (double*)alloc(NB * HD * 8);

    // prep: castx (+ zero cnt/pool) + all weight casts
    prep_kernel<<<5640, 256, 0, stream>>>(x, xb, cnt, pool, W1, W2, W3, w1t, w2t, w3t);
    count_kernel<<<(NE + 255) / 256, 256, 0, stream>>>(dst, cnt);
    scan_blk_kernel<<<SB, 256, 0, stream>>>(cnt, bsum, dinv);
    scan_fin_kernel<<<SB, 256, 0, stream>>>(bsum, cnt, rstart);
    bucket_kernel<<<(NE + 255) / 256, 256, 0, stream>>>(src, dst, cnt, edge2, dinv);

    const int FG = MP / 64;   // 626 blocks

    // layer 1: bufA = relu(agg(xb) @ W1 + b1)
    fused_kernel<FIN><<<FG, 512, 0, stream>>>(xb, w1t, b1, edge2, rstart, dinv, bufA);
    // layer 2: bufB = relu(agg(bufA) @ W2 + b2)
    fused_kernel<HD><<<FG, 512, 0, stream>>>(bufA, w2t, b2, edge2, rstart, dinv, bufB);
    // layer 3: bufA = relu(agg(bufB) @ W3 + b3)
    fused_kernel<HD><<<FG, 512, 0, stream>>>(bufB, w3t, b3, edge2, rstart, dinv, bufA);

    // mean pool + head
    colsum_kernel<<<NN / 32, 256, 0, stream>>>(bufA, pool);
    head_kernel<<<1, 256, 0, stream>>>(pool, Wl, bl, out);
}